// Round 1
// baseline (636.321 us; speedup 1.0000x reference)
//
#include <hip/hip_runtime.h>
#include <hip/hip_bf16.h>

typedef __attribute__((ext_vector_type(4))) float f32x4;
typedef __attribute__((ext_vector_type(8))) short bf16x8;
typedef __attribute__((ext_vector_type(4))) short short4v;

__device__ __forceinline__ short f2bf(float f) {
  union { float f; unsigned u; } x; x.f = f;
  unsigned r = x.u + 0x7fffu + ((x.u >> 16) & 1u);
  return (short)(r >> 16);
}

// ---------------- cast f32 -> bf16 (RNE), 4 elems/thread ----------------
__global__ __launch_bounds__(256) void cast_kernel(const float* __restrict__ in,
                                                   short* __restrict__ out, int n4) {
  int i = blockIdx.x * 256 + threadIdx.x;
  if (i < n4) {
    const float4 v = reinterpret_cast<const float4*>(in)[i];
    short4v s;
    s.x = f2bf(v.x); s.y = f2bf(v.y); s.z = f2bf(v.z); s.w = f2bf(v.w);
    reinterpret_cast<short4v*>(out)[i] = s;
  }
}

// ---------------- GEMM: C[M,N] = A[M,K] * B[N,K]^T  (bf16 in, CT out) ----------------
// 128x128 tile, BK=64, 4 waves (2x2), each wave 64x64 via 4x4 16x16x32 MFMA frags.
template<typename CT>
__global__ __launch_bounds__(256) void gemm_bt(const short* __restrict__ A,
                                               const short* __restrict__ B,
                                               CT* __restrict__ C,
                                               int M, int N, int K) {
  __shared__ short As[128][72];   // +8 bf16 pad: row stride 144B (16B aligned, 2-way banks)
  __shared__ short Bs[128][72];

  const int tid  = threadIdx.x;
  const int lane = tid & 63;
  const int w    = tid >> 6;
  const int l16  = lane & 15, g = lane >> 4;
  const int wr   = w >> 1, wc = w & 1;
  const long m0  = (long)blockIdx.y * 128;
  const long n0  = (long)blockIdx.x * 128;

  const f32x4 zero4 = {0.f, 0.f, 0.f, 0.f};
  f32x4 acc[4][4];
  #pragma unroll
  for (int a = 0; a < 4; a++)
    #pragma unroll
    for (int b2 = 0; b2 < 4; b2++) acc[a][b2] = zero4;

  const int srow0 = tid >> 3;        // 0..31 (+ j*32)
  const int scol  = (tid & 7) * 8;   // 0..56

  const int ktiles = K >> 6;
  for (int kt = 0; kt < ktiles; kt++) {
    const int k0 = kt << 6;
    __syncthreads();
    #pragma unroll
    for (int j = 0; j < 4; j++) {
      const int row = j * 32 + srow0;
      *reinterpret_cast<bf16x8*>(&As[row][scol]) =
          *reinterpret_cast<const bf16x8*>(A + (m0 + row) * K + k0 + scol);
      *reinterpret_cast<bf16x8*>(&Bs[row][scol]) =
          *reinterpret_cast<const bf16x8*>(B + (n0 + row) * K + k0 + scol);
    }
    __syncthreads();
    #pragma unroll
    for (int kk = 0; kk < 2; kk++) {
      bf16x8 af[4], bfr[4];
      #pragma unroll
      for (int f = 0; f < 4; f++)
        af[f] = *reinterpret_cast<const bf16x8*>(&As[wr * 64 + f * 16 + l16][kk * 32 + g * 8]);
      #pragma unroll
      for (int f = 0; f < 4; f++)
        bfr[f] = *reinterpret_cast<const bf16x8*>(&Bs[wc * 64 + f * 16 + l16][kk * 32 + g * 8]);
      #pragma unroll
      for (int fm = 0; fm < 4; fm++)
        #pragma unroll
        for (int fn = 0; fn < 4; fn++)
          acc[fm][fn] = __builtin_amdgcn_mfma_f32_16x16x32_bf16(af[fm], bfr[fn], acc[fm][fn], 0, 0, 0);
    }
  }

  // epilogue: D row = (lane>>4)*4 + i, col = lane&15  [m89-verified layout]
  #pragma unroll
  for (int fm = 0; fm < 4; fm++)
    #pragma unroll
    for (int fn = 0; fn < 4; fn++) {
      const long row = m0 + wr * 64 + fm * 16 + g * 4;
      const long col = n0 + wc * 64 + fn * 16 + l16;
      #pragma unroll
      for (int i = 0; i < 4; i++) {
        const float v = acc[fm][fn][i];
        if constexpr (sizeof(CT) == 2) C[(row + i) * N + col] = (CT)f2bf(v);
        else                           C[(row + i) * N + col] = v;
      }
    }
}

// ---------------- flash attention with causal + ALiBi ----------------
// grid (S/64, B*H); 4 waves, wave w owns q rows [q0+16w, q0+16w+16)
__global__ __launch_bounds__(256) void attn_kernel(const short* __restrict__ Q,
                                                   const short* __restrict__ K,
                                                   const short* __restrict__ V,
                                                   short* __restrict__ Z) {
  __shared__ short vt[128][40];        // V^T tile: vt[dh][kv], row stride 80B
  __shared__ short plds[4][16][40];    // per-wave P relayout buffer

  const int tid  = threadIdx.x;
  const int lane = tid & 63;
  const int w    = tid >> 6;
  const int l16  = lane & 15, g = lane >> 4;
  const int q0   = blockIdx.x * 64;
  const int bh   = blockIdx.y;
  const int b    = bh >> 4, h = bh & 15;
  const float slope = exp2f(-0.5f * (float)(h + 1));   // ALiBi slopes for H=16
  const float scale = 0.08838834764831845f;            // 1/sqrt(128)

  // Q fragments: A-frag row = l16, k = g*8 + j
  const int qrow = q0 + w * 16 + l16;
  const long qoff = ((long)(b * 2048 + qrow)) * 2048 + h * 128;
  bf16x8 qf[4];
  #pragma unroll
  for (int c = 0; c < 4; c++)
    qf[c] = *reinterpret_cast<const bf16x8*>(Q + qoff + c * 32 + g * 8);

  const f32x4 zero4 = {0.f, 0.f, 0.f, 0.f};
  f32x4 zacc[8];
  #pragma unroll
  for (int s = 0; s < 8; s++) zacc[s] = zero4;
  float mi[4] = {-3e38f, -3e38f, -3e38f, -3e38f};
  float li[4] = {0.f, 0.f, 0.f, 0.f};

  const int qiBase = q0 + w * 16 + g * 4;   // this lane's score rows (C layout)
  const int vdhc = (tid & 15) * 8;
  const int vkvr = tid >> 4;

  const int ntiles = (q0 >> 5) + 2;
  for (int t = 0; t < ntiles; t++) {
    const int kv0 = t * 32;

    __syncthreads();   // previous tile's PV reads of vt done
    // stage V^T: read 8 bf16 along dh, scatter-write transposed
    #pragma unroll
    for (int half = 0; half < 2; half++) {
      const int kvi = vkvr + half * 16;
      const bf16x8 vv = *reinterpret_cast<const bf16x8*>(
          V + ((long)(b * 2048 + kv0 + kvi)) * 2048 + h * 128 + vdhc);
      #pragma unroll
      for (int jj = 0; jj < 8; jj++) vt[vdhc + jj][kvi] = vv[jj];
    }
    __syncthreads();

    // QK^T: scores for 16 q x 32 kv per wave
    f32x4 sc[2];
    #pragma unroll
    for (int sub = 0; sub < 2; sub++) {
      f32x4 a = zero4;
      const long koff = ((long)(b * 2048 + kv0 + sub * 16 + l16)) * 2048 + h * 128;
      #pragma unroll
      for (int c = 0; c < 4; c++) {
        const bf16x8 kf = *reinterpret_cast<const bf16x8*>(K + koff + c * 32 + g * 8);
        a = __builtin_amdgcn_mfma_f32_16x16x32_bf16(qf[c], kf, a, 0, 0, 0);
      }
      sc[sub] = a;
    }

    // scale, clamp, ALiBi bias, causal mask, online softmax
    #pragma unroll
    for (int i = 0; i < 4; i++) {
      const int qi = qiBase + i;
      float best = -3e38f;
      #pragma unroll
      for (int sub = 0; sub < 2; sub++) {
        const int j = kv0 + sub * 16 + l16;
        float v = sc[sub][i] * scale;
        v = fminf(fmaxf(v, -1024.f), 1024.f) + slope * (float)j;
        v = (j <= qi) ? v : -3e38f;
        sc[sub][i] = v;
        best = fmaxf(best, v);
      }
      #pragma unroll
      for (int ms = 1; ms < 16; ms <<= 1) best = fmaxf(best, __shfl_xor(best, ms));
      const float mnew = fmaxf(mi[i], best);
      const float corr = __expf(mi[i] - mnew);
      mi[i] = mnew;
      float psum = 0.f;
      #pragma unroll
      for (int sub = 0; sub < 2; sub++) {
        const float sv = sc[sub][i];
        const float p = (sv > -1e37f) ? __expf(sv - mnew) : 0.f;  // masked -> 0
        sc[sub][i] = p;
        psum += p;
      }
      #pragma unroll
      for (int ms = 1; ms < 16; ms <<= 1) psum += __shfl_xor(psum, ms);
      li[i] = li[i] * corr + psum;
      #pragma unroll
      for (int s = 0; s < 8; s++) zacc[s][i] *= corr;
    }

    // P (C-layout) -> LDS -> A-frag layout, then PV
    #pragma unroll
    for (int i = 0; i < 4; i++) {
      plds[w][g * 4 + i][l16]      = f2bf(sc[0][i]);
      plds[w][g * 4 + i][16 + l16] = f2bf(sc[1][i]);
    }
    const bf16x8 pf = *reinterpret_cast<const bf16x8*>(&plds[w][l16][g * 8]);
    #pragma unroll
    for (int s = 0; s < 8; s++) {
      const bf16x8 vf = *reinterpret_cast<const bf16x8*>(&vt[s * 16 + l16][g * 8]);
      zacc[s] = __builtin_amdgcn_mfma_f32_16x16x32_bf16(pf, vf, zacc[s], 0, 0, 0);
    }
  }

  // normalize + write Z (bf16)
  #pragma unroll
  for (int s = 0; s < 8; s++)
    #pragma unroll
    for (int i = 0; i < 4; i++) {
      const int qi = qiBase + i;
      const float zv = zacc[s][i] / li[i];
      Z[((long)(b * 2048 + qi)) * 2048 + h * 128 + s * 16 + l16] = f2bf(zv);
    }
}

// ---------------- launch ----------------
extern "C" void kernel_launch(void* const* d_in, const int* in_sizes, int n_in,
                              void* d_out, int out_size, void* d_ws, size_t ws_size,
                              hipStream_t stream) {
  const float* X  = (const float*)d_in[0];
  const float* Wq = (const float*)d_in[1];
  const float* Wk = (const float*)d_in[2];
  const float* Wv = (const float*)d_in[3];
  const float* Wo = (const float*)d_in[4];
  float* out = (float*)d_out;

  short* ws  = (short*)d_ws;
  short* Xb  = ws;                 // 8,388,608 bf16 (reused as Zb after QKV)
  short* Wqb = ws + 8388608;
  short* Wkb = ws + 12582912;
  short* Wvb = ws + 16777216;
  short* Wob = ws + 20971520;
  short* Qb  = ws + 25165824;
  short* Kb  = ws + 33554432;
  short* Vb  = ws + 41943040;      // end at 50,331,648 shorts = ~96 MB
  short* Zb  = Xb;

  cast_kernel<<<8192, 256, 0, stream>>>(X,  Xb,  2097152);
  cast_kernel<<<4096, 256, 0, stream>>>(Wq, Wqb, 1048576);
  cast_kernel<<<4096, 256, 0, stream>>>(Wk, Wkb, 1048576);
  cast_kernel<<<4096, 256, 0, stream>>>(Wv, Wvb, 1048576);
  cast_kernel<<<4096, 256, 0, stream>>>(Wo, Wob, 1048576);

  dim3 gg(16, 32);   // (N/128, M/128)
  gemm_bt<short><<<gg, 256, 0, stream>>>(Xb, Wqb, Qb, 4096, 2048, 2048);
  gemm_bt<short><<<gg, 256, 0, stream>>>(Xb, Wkb, Kb, 4096, 2048, 2048);
  gemm_bt<short><<<gg, 256, 0, stream>>>(Xb, Wvb, Vb, 4096, 2048, 2048);

  dim3 ga(32, 32);   // (S/64, B*H)
  attn_kernel<<<ga, 256, 0, stream>>>(Qb, Kb, Vb, Zb);

  gemm_bt<float><<<gg, 256, 0, stream>>>(Zb, Wob, out, 4096, 2048, 2048);
}

// Round 2
// 335.377 us; speedup vs baseline: 1.8973x; 1.8973x over previous
//
#include <hip/hip_runtime.h>
#include <hip/hip_bf16.h>

typedef __attribute__((ext_vector_type(4))) float f32x4;
typedef __attribute__((ext_vector_type(8))) short bf16x8;
typedef __attribute__((ext_vector_type(4))) short short4v;

__device__ __forceinline__ short f2bf(float f) {
  union { float f; unsigned u; } x; x.f = f;
  unsigned r = x.u + 0x7fffu + ((x.u >> 16) & 1u);
  return (short)(r >> 16);
}

// ---------------- cast f32 -> bf16 (RNE), 4 elems/thread ----------------
__global__ __launch_bounds__(256) void cast_kernel(const float* __restrict__ in,
                                                   short* __restrict__ out, int n4) {
  int i = blockIdx.x * 256 + threadIdx.x;
  if (i < n4) {
    const float4 v = reinterpret_cast<const float4*>(in)[i];
    short4v s;
    s.x = f2bf(v.x); s.y = f2bf(v.y); s.z = f2bf(v.z); s.w = f2bf(v.w);
    reinterpret_cast<short4v*>(out)[i] = s;
  }
}

// ---------------- GEMM: C[M,N] = A[M,K] * B[N,K]^T  (bf16 in, CT out) ----------------
template<typename CT>
__global__ __launch_bounds__(256) void gemm_bt(const short* __restrict__ A,
                                               const short* __restrict__ B,
                                               CT* __restrict__ C,
                                               int M, int N, int K) {
  __shared__ short As[128][72];
  __shared__ short Bs[128][72];

  const int tid  = threadIdx.x;
  const int lane = tid & 63;
  const int w    = tid >> 6;
  const int l16  = lane & 15, g = lane >> 4;
  const int wr   = w >> 1, wc = w & 1;
  const long m0  = (long)blockIdx.y * 128;
  const long n0  = (long)blockIdx.x * 128;

  const f32x4 zero4 = {0.f, 0.f, 0.f, 0.f};
  f32x4 acc[4][4];
  #pragma unroll
  for (int a = 0; a < 4; a++)
    #pragma unroll
    for (int b2 = 0; b2 < 4; b2++) acc[a][b2] = zero4;

  const int srow0 = tid >> 3;
  const int scol  = (tid & 7) * 8;

  const int ktiles = K >> 6;
  for (int kt = 0; kt < ktiles; kt++) {
    const int k0 = kt << 6;
    __syncthreads();
    #pragma unroll
    for (int j = 0; j < 4; j++) {
      const int row = j * 32 + srow0;
      *reinterpret_cast<bf16x8*>(&As[row][scol]) =
          *reinterpret_cast<const bf16x8*>(A + (m0 + row) * K + k0 + scol);
      *reinterpret_cast<bf16x8*>(&Bs[row][scol]) =
          *reinterpret_cast<const bf16x8*>(B + (n0 + row) * K + k0 + scol);
    }
    __syncthreads();
    #pragma unroll
    for (int kk = 0; kk < 2; kk++) {
      bf16x8 af[4], bfr[4];
      #pragma unroll
      for (int f = 0; f < 4; f++)
        af[f] = *reinterpret_cast<const bf16x8*>(&As[wr * 64 + f * 16 + l16][kk * 32 + g * 8]);
      #pragma unroll
      for (int f = 0; f < 4; f++)
        bfr[f] = *reinterpret_cast<const bf16x8*>(&Bs[wc * 64 + f * 16 + l16][kk * 32 + g * 8]);
      #pragma unroll
      for (int fm = 0; fm < 4; fm++)
        #pragma unroll
        for (int fn = 0; fn < 4; fn++)
          acc[fm][fn] = __builtin_amdgcn_mfma_f32_16x16x32_bf16(af[fm], bfr[fn], acc[fm][fn], 0, 0, 0);
    }
  }

  #pragma unroll
  for (int fm = 0; fm < 4; fm++)
    #pragma unroll
    for (int fn = 0; fn < 4; fn++) {
      const long row = m0 + wr * 64 + fm * 16 + g * 4;
      const long col = n0 + wc * 64 + fn * 16 + l16;
      #pragma unroll
      for (int i = 0; i < 4; i++) {
        const float v = acc[fm][fn][i];
        if constexpr (sizeof(CT) == 2) C[(row + i) * N + col] = (CT)f2bf(v);
        else                           C[(row + i) * N + col] = v;
      }
    }
}

// ---------------- flash attention v2: QBLK=128 (32 q/wave), KVBLK=64 ----------------
// grid (16, 32); 4 waves. K staged in padded LDS, V^T staged swizzled, P via per-wave LDS.
__global__ __launch_bounds__(256) void attn_kernel(const short* __restrict__ Q,
                                                   const short* __restrict__ K,
                                                   const short* __restrict__ V,
                                                   short* __restrict__ Z) {
  __shared__ short Ks[64][136];        // 17408 B, stride 272B -> balanced b128 reads
  __shared__ short vtl[128 * 72];      // V^T, stride 144B, 16B-block XOR swizzle
  __shared__ short plds[4][32][72];    // per-wave P relayout

  const int tid  = threadIdx.x;
  const int lane = tid & 63;
  const int w    = tid >> 6;
  const int l16  = lane & 15, g = lane >> 4;

  // work-balancing remap: CU's two resident blocks get bx and 15-bx (work sums const)
  const int id   = blockIdx.x + (blockIdx.y << 4);    // 0..511, x-fastest dispatch order
  const int half = id >> 8, r = id & 255;
  const int bx   = half ? (15 - (r >> 5)) : (r >> 5);
  const int bh   = r & 31;
  const int b    = bh >> 4, h = bh & 15;
  const int q0   = bx * 128;
  const float slope = exp2f(-0.5f * (float)(h + 1));
  const float scale = 0.08838834764831845f;

  // Q in registers: 2 m-frags x 4 k-steps
  bf16x8 qf[2][4];
  #pragma unroll
  for (int mi = 0; mi < 2; mi++) {
    const long qoff = ((long)(b * 2048 + q0 + w * 32 + mi * 16 + l16)) * 2048 + h * 128;
    #pragma unroll
    for (int c = 0; c < 4; c++)
      qf[mi][c] = *reinterpret_cast<const bf16x8*>(Q + qoff + c * 32 + g * 8);
  }

  const f32x4 zero4 = {0.f, 0.f, 0.f, 0.f};
  f32x4 zacc[2][8];
  #pragma unroll
  for (int mi = 0; mi < 2; mi++)
    #pragma unroll
    for (int s = 0; s < 8; s++) zacc[mi][s] = zero4;
  float mrow[2][4], li[2][4];
  #pragma unroll
  for (int mi = 0; mi < 2; mi++)
    #pragma unroll
    for (int i = 0; i < 4; i++) { mrow[mi][i] = -3e38f; li[mi][i] = 0.f; }

  const int ntiles = 2 * bx + 2;
  for (int t = 0; t < ntiles; t++) {
    const int kv0 = t * 64;
    __syncthreads();   // prev tile's MFMA reads of Ks/vtl done

    // stage K [64][128] -> Ks, coalesced (4 rows x 256B per wave-instr)
    {
      const short* Kbase = K + ((long)(b * 2048 + kv0)) * 2048 + h * 128;
      const int col = (tid & 15) * 8;
      #pragma unroll
      for (int j = 0; j < 4; j++) {
        const int row = j * 16 + (tid >> 4);
        *reinterpret_cast<bf16x8*>(&Ks[row][col]) =
            *reinterpret_cast<const bf16x8*>(Kbase + (long)row * 2048 + col);
      }
    }
    // stage V^T swizzled: lane = kv row -> writes spread linearly over banks (free)
    {
      const short* Vbase = V + ((long)(b * 2048 + kv0 + lane)) * 2048 + h * 128 + w * 32;
      #pragma unroll
      for (int rep = 0; rep < 4; rep++) {
        const bf16x8 vv = *reinterpret_cast<const bf16x8*>(Vbase + rep * 8);
        #pragma unroll
        for (int jj = 0; jj < 8; jj++) {
          const int dh = w * 32 + rep * 8 + jj;
          const int a  = dh * 144 + ((lane * 2) ^ (((dh >> 3) & 7) << 4));
          *reinterpret_cast<short*>(reinterpret_cast<char*>(vtl) + a) = vv[jj];
        }
      }
    }
    __syncthreads();

    // QK^T: 32 q x 64 kv per wave
    f32x4 sc[2][4];
    #pragma unroll
    for (int mi = 0; mi < 2; mi++)
      #pragma unroll
      for (int ni = 0; ni < 4; ni++) sc[mi][ni] = zero4;
    #pragma unroll
    for (int ni = 0; ni < 4; ni++)
      #pragma unroll
      for (int kc = 0; kc < 4; kc++) {
        const bf16x8 kf = *reinterpret_cast<const bf16x8*>(&Ks[ni * 16 + l16][kc * 32 + g * 8]);
        #pragma unroll
        for (int mi = 0; mi < 2; mi++)
          sc[mi][ni] = __builtin_amdgcn_mfma_f32_16x16x32_bf16(qf[mi][kc], kf, sc[mi][ni], 0, 0, 0);
      }

    // softmax (online): scale, clamp, +alibi, causal mask
    #pragma unroll
    for (int mi = 0; mi < 2; mi++)
      #pragma unroll
      for (int i = 0; i < 4; i++) {
        const int qi = q0 + w * 32 + mi * 16 + g * 4 + i;
        float best = -3e38f;
        #pragma unroll
        for (int ni = 0; ni < 4; ni++) {
          const int j = kv0 + ni * 16 + l16;
          float v = sc[mi][ni][i] * scale;
          v = fminf(fmaxf(v, -1024.f), 1024.f) + slope * (float)j;
          v = (j <= qi) ? v : -3e38f;
          sc[mi][ni][i] = v;
          best = fmaxf(best, v);
        }
        #pragma unroll
        for (int ms = 1; ms < 16; ms <<= 1) best = fmaxf(best, __shfl_xor(best, ms));
        const float mnew = fmaxf(mrow[mi][i], best);
        const float corr = __expf(mrow[mi][i] - mnew);
        mrow[mi][i] = mnew;
        float psum = 0.f;
        #pragma unroll
        for (int ni = 0; ni < 4; ni++) {
          const float sv = sc[mi][ni][i];
          const float p = (sv > -1e37f) ? __expf(sv - mnew) : 0.f;
          sc[mi][ni][i] = p;
          psum += p;
        }
        #pragma unroll
        for (int ms = 1; ms < 16; ms <<= 1) psum += __shfl_xor(psum, ms);
        li[mi][i] = li[mi][i] * corr + psum;
        #pragma unroll
        for (int s = 0; s < 8; s++) zacc[mi][s][i] *= corr;
      }

    // P (C-layout) -> per-wave LDS -> A-frags
    #pragma unroll
    for (int mi = 0; mi < 2; mi++)
      #pragma unroll
      for (int ni = 0; ni < 4; ni++)
        #pragma unroll
        for (int i = 0; i < 4; i++)
          plds[w][mi * 16 + g * 4 + i][ni * 16 + l16] = f2bf(sc[mi][ni][i]);
    bf16x8 paf[2][2];
    #pragma unroll
    for (int mi = 0; mi < 2; mi++)
      #pragma unroll
      for (int kk = 0; kk < 2; kk++)
        paf[mi][kk] = *reinterpret_cast<const bf16x8*>(&plds[w][mi * 16 + l16][kk * 32 + g * 8]);

    // PV: Z[32q][128dh] += P[32q][64kv] * V^T
    #pragma unroll
    for (int s = 0; s < 8; s++) {
      const int rowb = s * 16 + l16;
      const int swz  = ((rowb >> 3) & 7) << 4;
      const bf16x8 vf0 = *reinterpret_cast<const bf16x8*>(
          reinterpret_cast<char*>(vtl) + rowb * 144 + ((g * 16) ^ swz));
      const bf16x8 vf1 = *reinterpret_cast<const bf16x8*>(
          reinterpret_cast<char*>(vtl) + rowb * 144 + ((64 + g * 16) ^ swz));
      #pragma unroll
      for (int mi = 0; mi < 2; mi++) {
        zacc[mi][s] = __builtin_amdgcn_mfma_f32_16x16x32_bf16(paf[mi][0], vf0, zacc[mi][s], 0, 0, 0);
        zacc[mi][s] = __builtin_amdgcn_mfma_f32_16x16x32_bf16(paf[mi][1], vf1, zacc[mi][s], 0, 0, 0);
      }
    }
  }

  // normalize + write Z
  #pragma unroll
  for (int mi = 0; mi < 2; mi++)
    #pragma unroll
    for (int s = 0; s < 8; s++)
      #pragma unroll
      for (int i = 0; i < 4; i++) {
        const int qi = q0 + w * 32 + mi * 16 + g * 4 + i;
        const float zv = zacc[mi][s][i] / li[mi][i];
        Z[((long)(b * 2048 + qi)) * 2048 + h * 128 + s * 16 + l16] = f2bf(zv);
      }
}

// ---------------- launch ----------------
extern "C" void kernel_launch(void* const* d_in, const int* in_sizes, int n_in,
                              void* d_out, int out_size, void* d_ws, size_t ws_size,
                              hipStream_t stream) {
  const float* X  = (const float*)d_in[0];
  const float* Wq = (const float*)d_in[1];
  const float* Wk = (const float*)d_in[2];
  const float* Wv = (const float*)d_in[3];
  const float* Wo = (const float*)d_in[4];
  float* out = (float*)d_out;

  short* ws  = (short*)d_ws;
  short* Xb  = ws;
  short* Wqb = ws + 8388608;
  short* Wkb = ws + 12582912;
  short* Wvb = ws + 16777216;
  short* Wob = ws + 20971520;
  short* Qb  = ws + 25165824;
  short* Kb  = ws + 33554432;
  short* Vb  = ws + 41943040;
  short* Zb  = Xb;

  cast_kernel<<<8192, 256, 0, stream>>>(X,  Xb,  2097152);
  cast_kernel<<<4096, 256, 0, stream>>>(Wq, Wqb, 1048576);
  cast_kernel<<<4096, 256, 0, stream>>>(Wk, Wkb, 1048576);
  cast_kernel<<<4096, 256, 0, stream>>>(Wv, Wvb, 1048576);
  cast_kernel<<<4096, 256, 0, stream>>>(Wo, Wob, 1048576);

  dim3 gg(16, 32);
  gemm_bt<short><<<gg, 256, 0, stream>>>(Xb, Wqb, Qb, 4096, 2048, 2048);
  gemm_bt<short><<<gg, 256, 0, stream>>>(Xb, Wkb, Kb, 4096, 2048, 2048);
  gemm_bt<short><<<gg, 256, 0, stream>>>(Xb, Wvb, Vb, 4096, 2048, 2048);

  dim3 ga(16, 32);
  attn_kernel<<<ga, 256, 0, stream>>>(Qb, Kb, Vb, Zb);

  gemm_bt<float><<<gg, 256, 0, stream>>>(Zb, Wob, out, 4096, 2048, 2048);
}